// Round 1
// baseline (355.986 us; speedup 1.0000x reference)
//
#include <hip/hip_runtime.h>

// out[i] = (a+d) + sqrt(|a*d - b*c|) for each contiguous 2x2 fp32 block.
// Memory-bound: 16 B read + 4 B write per row. float4 load = 16 B/lane
// coalescing sweet spot; scalar store is contiguous across lanes.
__global__ __launch_bounds__(256)
void MyModel_61933428415478_kernel(const float4* __restrict__ x,
                                   float* __restrict__ out, int n) {
    int i = blockIdx.x * blockDim.x + threadIdx.x;
    if (i < n) {
        float4 v = x[i];                      // v.x=a v.y=b v.z=c v.w=d
        float det = v.x * v.w - v.y * v.z;
        out[i] = (v.x + v.w) + sqrtf(fabsf(det));
    }
}

extern "C" void kernel_launch(void* const* d_in, const int* in_sizes, int n_in,
                              void* d_out, int out_size, void* d_ws, size_t ws_size,
                              hipStream_t stream) {
    const float4* x = (const float4*)d_in[0];
    float* out = (float*)d_out;
    int n = in_sizes[0] >> 2;                 // flat count / 4 = number of 2x2 rows
    int block = 256;
    int grid = (n + block - 1) / block;
    MyModel_61933428415478_kernel<<<grid, block, 0, stream>>>(x, out, n);
}